// Round 1
// baseline (513.459 us; speedup 1.0000x reference)
//
#include <hip/hip_runtime.h>
#include <hip/hip_bf16.h>
#include <math.h>

typedef __bf16 bf16x8 __attribute__((ext_vector_type(8)));
typedef float  f32x4  __attribute__((ext_vector_type(4)));
typedef __hip_bfloat16 bf16;

#define DIM  1024
#define MLPD 4096
#define NB   4
#define SEQ  2048
#define ROWS (NB * SEQ) /* 8192 */

__device__ __forceinline__ void gload_lds16(const void* g, void* l) {
  __builtin_amdgcn_global_load_lds(
      (__attribute__((address_space(1))) void*)(g),
      (__attribute__((address_space(3))) void*)(l), 16, 0, 0);
}

__device__ __forceinline__ bf16 to_bf16(float v) { return __float2bfloat16(v); }
__device__ __forceinline__ bf16 to_bf16(bf16 v)  { return v; }

// ---------------------------------------------------------------------------
// GEMM: C[M][N] = A[M][K](bf16) @ Bt[N][K]^T(bf16), m97 structure (128x128,BK=32)
// EPI: 0 = +bias -> bf16 | 1 = *scale -> fp32 | 2 = +resid -> fp32
//      3 = +bias,gelu -> bf16 | 4 = +bias+resid -> fp32
// ---------------------------------------------------------------------------
template <int EPI>
__global__ __launch_bounds__(256) void gemm_bt(
    const bf16* __restrict__ A,  long aBatch, int lda,
    const bf16* __restrict__ Bt, long bBatch, int ldb,
    void* __restrict__ Cout,     long cBatch, int ldc,
    const float* __restrict__ bias,
    const float* __restrict__ resid, long rBatch, int ldr,
    int K, float scale)
{
  __shared__ alignas(16) bf16 Al[128][32];
  __shared__ alignas(16) bf16 Bl[128][32];

  const int  bz      = blockIdx.z;
  const long rowBase = (long)blockIdx.y * 128;
  const long colBase = (long)blockIdx.x * 128;
  const bf16* Ap = A  + bz * aBatch + rowBase * lda;
  const bf16* Bp = Bt + bz * bBatch + colBase * ldb;

  const int tid  = threadIdx.x;
  const int lane = tid & 63;
  const int wave = tid >> 6;
  const int wr   = (wave >> 1) * 64;   // wave row origin in tile
  const int wc   = (wave & 1) * 64;    // wave col origin in tile
  const int fr   = lane & 15;
  const int fq   = lane >> 4;
  const int srow = tid >> 2;           // staging row 0..63
  const int skc  = (tid & 3) * 8;      // staging k offset (elements)

  f32x4 acc[4][4] = {};

  for (int k0 = 0; k0 < K; k0 += 32) {
    __syncthreads();
    gload_lds16(Ap + (long)srow * lda + k0 + skc,        &Al[srow][skc]);
    gload_lds16(Ap + (long)(srow + 64) * lda + k0 + skc, &Al[srow + 64][skc]);
    gload_lds16(Bp + (long)srow * ldb + k0 + skc,        &Bl[srow][skc]);
    gload_lds16(Bp + (long)(srow + 64) * ldb + k0 + skc, &Bl[srow + 64][skc]);
    __syncthreads();

    bf16x8 af[4], bf[4];
#pragma unroll
    for (int m = 0; m < 4; ++m)
      af[m] = *(const bf16x8*)&Al[wr + m * 16 + fr][fq * 8];
#pragma unroll
    for (int n = 0; n < 4; ++n)
      bf[n] = *(const bf16x8*)&Bl[wc + n * 16 + fr][fq * 8];
#pragma unroll
    for (int m = 0; m < 4; ++m)
#pragma unroll
      for (int n = 0; n < 4; ++n)
        acc[m][n] = __builtin_amdgcn_mfma_f32_16x16x32_bf16(af[m], bf[n], acc[m][n], 0, 0, 0);
  }

#pragma unroll
  for (int m = 0; m < 4; ++m) {
#pragma unroll
    for (int n = 0; n < 4; ++n) {
      const long col = colBase + wc + n * 16 + fr;
#pragma unroll
      for (int e = 0; e < 4; ++e) {
        const long r = rowBase + wr + m * 16 + fq * 4 + e;
        float v = acc[m][n][e];
        if constexpr (EPI == 0) {
          v += bias[col];
          ((bf16*)Cout)[bz * cBatch + r * ldc + col] = __float2bfloat16(v);
        } else if constexpr (EPI == 1) {
          ((float*)Cout)[bz * cBatch + r * ldc + col] = v * scale;
        } else if constexpr (EPI == 2) {
          v += resid[bz * rBatch + r * ldr + col];
          ((float*)Cout)[bz * cBatch + r * ldc + col] = v;
        } else if constexpr (EPI == 3) {
          v += bias[col];
          const float gl = 0.5f * v * (1.0f + erff(v * 0.70710678118654752f));
          ((bf16*)Cout)[bz * cBatch + r * ldc + col] = __float2bfloat16(gl);
        } else {
          v += bias[col] + resid[r * (long)ldr + col];
          ((float*)Cout)[bz * cBatch + r * ldc + col] = v;
        }
      }
    }
  }
}

// ---------------------------------------------------------------------------
// LayerNorm over DIM=1024, one block per row, fp32 in -> bf16 out
// ---------------------------------------------------------------------------
__global__ __launch_bounds__(256) void ln_kernel(
    const float* __restrict__ x, const float* __restrict__ gamma,
    const float* __restrict__ beta, bf16* __restrict__ out)
{
  const long row = blockIdx.x;
  const float4 v = ((const float4*)(x + row * DIM))[threadIdx.x];
  float s  = v.x + v.y + v.z + v.w;
  float ss = v.x * v.x + v.y * v.y + v.z * v.z + v.w * v.w;
  const int lane = threadIdx.x & 63, wave = threadIdx.x >> 6;
#pragma unroll
  for (int o = 32; o; o >>= 1) { s += __shfl_xor(s, o); ss += __shfl_xor(ss, o); }
  __shared__ float rs[4], rss[4];
  if (lane == 0) { rs[wave] = s; rss[wave] = ss; }
  __syncthreads();
  s  = rs[0] + rs[1] + rs[2] + rs[3];
  ss = rss[0] + rss[1] + rss[2] + rss[3];
  const float mean = s * (1.0f / DIM);
  const float var  = ss * (1.0f / DIM) - mean * mean;
  const float rstd = rsqrtf(var + 1e-5f);
  const float4 g = ((const float4*)gamma)[threadIdx.x];
  const float4 b = ((const float4*)beta)[threadIdx.x];
  union { bf16 h[4]; uint2 u; } pk;
  pk.h[0] = __float2bfloat16(g.x * (v.x - mean) * rstd + b.x);
  pk.h[1] = __float2bfloat16(g.y * (v.y - mean) * rstd + b.y);
  pk.h[2] = __float2bfloat16(g.z * (v.z - mean) * rstd + b.z);
  pk.h[3] = __float2bfloat16(g.w * (v.w - mean) * rstd + b.w);
  ((uint2*)(out + row * DIM))[threadIdx.x] = pk.u;
}

// ---------------------------------------------------------------------------
// Row softmax over SEQ=2048 fp32 scores, write bf16 P in-place (row stride
// stays 8192 bytes => 4096 bf16 elements)
// ---------------------------------------------------------------------------
__global__ __launch_bounds__(256) void softmax_kernel(float* __restrict__ scores)
{
  const long row = blockIdx.x;
  float* rp = scores + row * (long)SEQ;
  const float4 v0 = ((const float4*)rp)[threadIdx.x * 2];
  const float4 v1 = ((const float4*)rp)[threadIdx.x * 2 + 1];
  float f[8] = {v0.x, v0.y, v0.z, v0.w, v1.x, v1.y, v1.z, v1.w};
  const int lane = threadIdx.x & 63, wave = threadIdx.x >> 6;
  float mx = f[0];
#pragma unroll
  for (int j = 1; j < 8; ++j) mx = fmaxf(mx, f[j]);
#pragma unroll
  for (int o = 32; o; o >>= 1) mx = fmaxf(mx, __shfl_xor(mx, o));
  __shared__ float rm[4], rsum[4];
  if (lane == 0) rm[wave] = mx;
  __syncthreads();
  mx = fmaxf(fmaxf(rm[0], rm[1]), fmaxf(rm[2], rm[3]));
  float sum = 0.0f;
#pragma unroll
  for (int j = 0; j < 8; ++j) { f[j] = expf(f[j] - mx); sum += f[j]; }
#pragma unroll
  for (int o = 32; o; o >>= 1) sum += __shfl_xor(sum, o);
  if (lane == 0) rsum[wave] = sum;
  __syncthreads();
  sum = rsum[0] + rsum[1] + rsum[2] + rsum[3];
  const float inv = 1.0f / sum;
  union { bf16 h[8]; uint4 u; } pk;
#pragma unroll
  for (int j = 0; j < 8; ++j) pk.h[j] = __float2bfloat16(f[j] * inv);
  bf16* prow = (bf16*)scores + row * (long)(2 * SEQ);
  ((uint4*)prow)[threadIdx.x] = pk.u;
}

// ---------------------------------------------------------------------------
// Tiled transpose + convert to bf16: in[R][C] -> out[C][R]
// ---------------------------------------------------------------------------
template <typename TI>
__global__ __launch_bounds__(256) void transpose_bf16_kernel(
    const TI* __restrict__ in, bf16* __restrict__ out,
    int R, int C, long inBatch, long outBatch)
{
  __shared__ bf16 tile[32][33];
  const long zin  = (long)blockIdx.z * inBatch;
  const long zout = (long)blockIdx.z * outBatch;
  const int c0 = blockIdx.x * 32, r0 = blockIdx.y * 32;
  const int tx = threadIdx.x & 31, ty = threadIdx.x >> 5;  // 32 x 8
#pragma unroll
  for (int i = 0; i < 32; i += 8)
    tile[ty + i][tx] = to_bf16(in[zin + (long)(r0 + ty + i) * C + c0 + tx]);
  __syncthreads();
#pragma unroll
  for (int i = 0; i < 32; i += 8)
    out[zout + (long)(c0 + ty + i) * R + r0 + tx] = tile[tx][ty + i];
}

// ---------------------------------------------------------------------------
extern "C" void kernel_launch(void* const* d_in, const int* in_sizes, int n_in,
                              void* d_out, int out_size, void* d_ws, size_t ws_size,
                              hipStream_t stream) {
  const float* x   = (const float*)d_in[0];
  const float* g1  = (const float*)d_in[1];
  const float* be1 = (const float*)d_in[2];
  const float* g2  = (const float*)d_in[3];
  const float* be2 = (const float*)d_in[4];
  const float* Wq  = (const float*)d_in[5];
  const float* bq  = (const float*)d_in[6];
  const float* Wk  = (const float*)d_in[7];
  const float* bk  = (const float*)d_in[8];
  const float* Wv  = (const float*)d_in[9];
  const float* bv  = (const float*)d_in[10];
  const float* W1  = (const float*)d_in[11];
  const float* b1  = (const float*)d_in[12];
  const float* W2  = (const float*)d_in[13];
  const float* b2  = (const float*)d_in[14];
  float* out = (float*)d_out;

  char* ws = (char*)d_ws;
  // workspace arena (bytes)
  bf16* WqT = (bf16*)(ws + 0);           // 2 MiB  [1024][1024]
  bf16* WkT = (bf16*)(ws + (2l << 20));
  bf16* WvT = (bf16*)(ws + (4l << 20));
  bf16* W1T = (bf16*)(ws + (6l << 20));  // 8 MiB  [4096][1024]
  bf16* W2T = (bf16*)(ws + (14l << 20)); // 8 MiB  [1024][4096]
  bf16* h   = (bf16*)(ws + (22l << 20)); // 16 MiB [8192][1024] (LN1 out, later LN2 out)
  bf16* q   = (bf16*)(ws + (38l << 20)); // 16 MiB
  bf16* k   = (bf16*)(ws + (54l << 20)); // 16 MiB
  bf16* v   = (bf16*)(ws + (70l << 20)); // 16 MiB
  bf16* vT  = (bf16*)(ws + (86l << 20)); // 16 MiB [b][1024][2048]
  float* sc = (float*)(ws + (102l << 20)); // 64 MiB scores fp32 / later g bf16
  bf16* P   = (bf16*)sc;                   // bf16 alias, row stride 4096
  bf16* g_act = (bf16*)sc;                 // [8192][4096] gelu out (reuse)

  const dim3 blk(256);

  // 1. weight transpose+convert
  transpose_bf16_kernel<float><<<dim3(32, 32, 1), blk, 0, stream>>>(Wq, WqT, 1024, 1024, 0, 0);
  transpose_bf16_kernel<float><<<dim3(32, 32, 1), blk, 0, stream>>>(Wk, WkT, 1024, 1024, 0, 0);
  transpose_bf16_kernel<float><<<dim3(32, 32, 1), blk, 0, stream>>>(Wv, WvT, 1024, 1024, 0, 0);
  transpose_bf16_kernel<float><<<dim3(128, 32, 1), blk, 0, stream>>>(W1, W1T, 1024, 4096, 0, 0);
  transpose_bf16_kernel<float><<<dim3(32, 128, 1), blk, 0, stream>>>(W2, W2T, 4096, 1024, 0, 0);

  // 2. LN1: x -> h (bf16)
  ln_kernel<<<ROWS, blk, 0, stream>>>(x, g1, be1, h);

  // 3. QKV projections (+bias) -> bf16
  gemm_bt<0><<<dim3(8, 64, 1), blk, 0, stream>>>(h, 0, DIM, WqT, 0, DIM, q, 0, DIM,
                                                 bq, nullptr, 0, 0, DIM, 1.0f);
  gemm_bt<0><<<dim3(8, 64, 1), blk, 0, stream>>>(h, 0, DIM, WkT, 0, DIM, k, 0, DIM,
                                                 bk, nullptr, 0, 0, DIM, 1.0f);
  gemm_bt<0><<<dim3(8, 64, 1), blk, 0, stream>>>(h, 0, DIM, WvT, 0, DIM, v, 0, DIM,
                                                 bv, nullptr, 0, 0, DIM, 1.0f);

  // 4. v -> vT per batch
  transpose_bf16_kernel<bf16><<<dim3(32, 64, NB), blk, 0, stream>>>(
      v, vT, SEQ, DIM, (long)SEQ * DIM, (long)SEQ * DIM);

  // 5. scores = q @ k^T * (1/32), fp32, batched
  gemm_bt<1><<<dim3(16, 16, NB), blk, 0, stream>>>(
      q, (long)SEQ * DIM, DIM, k, (long)SEQ * DIM, DIM,
      sc, (long)SEQ * SEQ, SEQ, nullptr, nullptr, 0, 0, DIM, 0.03125f);

  // 6. softmax rows (in-place, bf16 out with row stride 4096)
  softmax_kernel<<<ROWS, blk, 0, stream>>>(sc);

  // 7. x1 = P @ V + x  -> d_out (fp32), batched
  gemm_bt<2><<<dim3(8, 16, NB), blk, 0, stream>>>(
      P, (long)SEQ * 2 * SEQ, 2 * SEQ, vT, (long)DIM * SEQ, SEQ,
      out, (long)SEQ * DIM, DIM, nullptr, x, (long)SEQ * DIM, DIM, SEQ, 1.0f);

  // 8. LN2: d_out -> h (bf16)
  ln_kernel<<<ROWS, blk, 0, stream>>>(out, g2, be2, h);

  // 9. MLP1: gelu(h @ W1 + b1) -> g_act (bf16)
  gemm_bt<3><<<dim3(32, 64, 1), blk, 0, stream>>>(
      h, 0, DIM, W1T, 0, DIM, g_act, 0, MLPD, b1, nullptr, 0, 0, DIM, 1.0f);

  // 10. out = g_act @ W2 + b2 + x1(d_out)
  gemm_bt<4><<<dim3(8, 64, 1), blk, 0, stream>>>(
      g_act, 0, MLPD, W2T, 0, MLPD, out, 0, DIM, b2, out, 0, DIM, MLPD, 1.0f);
}